// Round 3
// baseline (658.039 us; speedup 1.0000x reference)
//
#include <hip/hip_runtime.h>
#include <math.h>

#define BB 4
#define NN 4096

// workspace layout (float offsets)
#define OFF_W0S   0        // 256: w0*s0 [c][4]
#define OFF_B0F   256      // 64: fused bias0
#define OFF_W1T   320      // 4096: W1T[c][o] = w1[o][c]*s1[o]
#define OFF_B1    4416     // 64
#define OFF_W2    4480     // 8192: W2[o][c]*s2[o]
#define OFF_B2    12672    // 128
#define NWTS      12800    // total weight floats (50 KB)
#define OFF_PACK  12800    // float4 refs [set][b][j] = (x,y,z,|r|^2)  (131072 floats)
#define OFF_IDX   143872   // int knn idx [b][n][32] (524288 ints)

typedef float v2f __attribute__((ext_vector_type(2)));

static __device__ __forceinline__ v2f vfma2(v2f a, v2f b, v2f c) {
#if __has_builtin(__builtin_elementwise_fma)
  return __builtin_elementwise_fma(a, b, c);
#else
  v2f r; r.x = fmaf(a.x, b.x, c.x); r.y = fmaf(a.y, b.y, c.y); return r;
#endif
}
static __device__ __forceinline__ v2f vmax2(v2f a, v2f b) {
#if __has_builtin(__builtin_elementwise_max)
  return __builtin_elementwise_max(a, b);
#else
  v2f r; r.x = fmaxf(a.x, b.x); r.y = fmaxf(a.y, b.y); return r;
#endif
}
static __device__ __forceinline__ v2f mkv2(float a, float b) {
  v2f r; r.x = a; r.y = b; return r;
}

__global__ __launch_bounds__(256) void prep_kernel(
    const float* __restrict__ p1, const float* __restrict__ p2,
    const float* __restrict__ w0, const float* __restrict__ b0, const float* __restrict__ g0,
    const float* __restrict__ be0, const float* __restrict__ m0, const float* __restrict__ v0,
    const float* __restrict__ w1, const float* __restrict__ b1, const float* __restrict__ g1,
    const float* __restrict__ be1, const float* __restrict__ m1, const float* __restrict__ v1,
    const float* __restrict__ w2, const float* __restrict__ b2, const float* __restrict__ g2,
    const float* __restrict__ be2, const float* __restrict__ m2, const float* __restrict__ v2,
    float* __restrict__ ws) {
  int gid = blockIdx.x * 256 + threadIdx.x;
  if (gid < 2 * BB * NN) {
    int set = gid >> 14;
    int rem = gid & (BB * NN - 1);
    int b = rem >> 12, j = rem & (NN - 1);
    const float* p = set ? p2 : p1;
    float x = p[(b * 3 + 0) * NN + j];
    float y = p[(b * 3 + 1) * NN + j];
    float z = p[(b * 3 + 2) * NN + j];
    ((float4*)(ws + OFF_PACK))[gid] = make_float4(x, y, z, x * x + y * y + z * z);
  }
  if (gid < 256) {                         // W0S[c][4]
    int c = gid >> 2, f = gid & 3;
    float s = g0[c] / sqrtf(v0[c] + 1e-3f);
    ws[OFF_W0S + gid] = w0[c * 4 + f] * s;
  } else if (gid < 320) {                  // B0F
    int c = gid - 256;
    float s = g0[c] / sqrtf(v0[c] + 1e-3f);
    ws[OFF_B0F + c] = (b0[c] - m0[c]) * s + be0[c];
  } else if (gid < 4416) {                 // W1T[c][o]
    int wg = gid - 320;
    int c = wg >> 6, o = wg & 63;
    float s = g1[o] / sqrtf(v1[o] + 1e-3f);
    ws[OFF_W1T + wg] = w1[o * 64 + c] * s;
  } else if (gid < 4480) {                 // B1
    int o = gid - 4416;
    float s = g1[o] / sqrtf(v1[o] + 1e-3f);
    ws[OFF_B1 + o] = (b1[o] - m1[o]) * s + be1[o];
  } else if (gid < 12672) {                // W2[o][c]
    int wg = gid - 4480;
    int o = wg >> 6;
    float s = g2[o] / sqrtf(v2[o] + 1e-3f);
    ws[OFF_W2 + wg] = w2[wg] * s;
  } else if (gid < 12800) {                // B2
    int o = gid - 12672;
    float s = g2[o] / sqrtf(v2[o] + 1e-3f);
    ws[OFF_B2 + o] = (b2[o] - m2[o]) * s + be2[o];
  }
}

__device__ __forceinline__ float distf(float qx, float qy, float qz, float qq,
                                       const float4& rv) {
  // pinned op order: identical codegen in every pass (bitwise-reproducible d)
  float dt = fmaf(qx, rv.x, fmaf(qy, rv.y, qz * rv.z));
  return fmaxf(fmaf(-2.f, dt, qq + rv.w), 0.f);
}

__device__ __forceinline__ void ins16(float (&bd)[16], float t) {
#pragma unroll
  for (int i = 0; i < 16; ++i) { float lo = fminf(t, bd[i]); t = fmaxf(t, bd[i]); bd[i] = lo; }
}

__device__ __forceinline__ void argmin8(const float (&d)[8], float& m, int& mi) {
  float ma = fminf(d[0], d[1]); int ia = (d[1] < d[0]) ? 1 : 0;
  float mb = fminf(d[2], d[3]); int ib = (d[3] < d[2]) ? 3 : 2;
  float mc = fminf(d[4], d[5]); int ic = (d[5] < d[4]) ? 5 : 4;
  float md = fminf(d[6], d[7]); int id = (d[7] < d[6]) ? 7 : 6;
  float me = fminf(ma, mb);     int ie = (mb < ma) ? ib : ia;
  float mf = fminf(mc, md);     int ig = (md < mc) ? id : ic;
  m = fminf(me, mf);            mi = (mf < me) ? ig : ie;
}

// grid: 512 blocks (set | chunk | b), 256 threads = 64 queries x 4 ref-splits.
// pass1: keys-only exact top-16 per (query,split), LDS-tiled refs, batch-8 argmin
// prefilter. merge -> exact global top-16 values + thr. pass2: collect (d,idx)
// candidates d<=thr. pass3: exact rank placement incl. O(C^2) tie resolution.
__global__ __launch_bounds__(256) void knn_kernel(const float* __restrict__ p1,
                                                  const float4* __restrict__ pkall,
                                                  int* __restrict__ idx_out) {
  __shared__ __align__(16) float4 tiles[4][2][64];   // 8 KB per-wave dbuf ref tiles
  __shared__ float skeys[256 * 17];                  // 17 KB sorted keys per thread
  __shared__ float sbd[64 * 17];                     // 4.25 KB merged top-16 per query
  __shared__ uint2 cand[4][16][64];                  // 32 KB [split][slot][query]
  __shared__ int ccnt[4][64];

  const int tid = threadIdx.x;
  const int lane = tid & 63;
  const int wv = tid >> 6;
  const int set = blockIdx.x & 1;
  const int chunk = (blockIdx.x >> 1) & 63;
  const int b = blockIdx.x >> 7;
  const int n = (chunk << 6) | lane;

  const float qx = p1[(b * 3 + 0) * NN + n];
  const float qy = p1[(b * 3 + 1) * NN + n];
  const float qz = p1[(b * 3 + 2) * NN + n];
  const float qq = qx * qx + qy * qy + qz * qz;

  const float4* __restrict__ pk = pkall + (size_t)(set * BB + b) * NN;
  const int j0 = wv << 10;

  // ---------------- pass 1: exact top-16 distance values ----------------
  float bd[16];
#pragma unroll
  for (int i = 0; i < 16; ++i) bd[i] = INFINITY;
  float worst = INFINITY;

  {
    float4 ld = pk[j0 + lane];
    for (int t = 0; t < 16; ++t) {
      const int buf = t & 1;
      tiles[wv][buf][lane] = ld;               // wave-private; DS pipe is in-order
      if (t < 15) ld = pk[j0 + ((t + 1) << 6) + lane];
#pragma unroll 1
      for (int g = 0; g < 8; ++g) {
        float d[8];
#pragma unroll
        for (int r = 0; r < 8; ++r)
          d[r] = distf(qx, qy, qz, qq, tiles[wv][buf][(g << 3) | r]);
        float m; int mi;
        argmin8(d, m, mi);
        while (m < worst) {
          ins16(bd, m);
          worst = bd[15];
#pragma unroll
          for (int r = 0; r < 8; ++r) d[r] = (r == mi) ? INFINITY : d[r];
          argmin8(d, m, mi);
        }
      }
    }
  }

#pragma unroll
  for (int i = 0; i < 16; ++i) skeys[tid * 17 + i] = bd[i];
  __syncthreads();

  // ---------------- merge 4 sorted lists (wave 0) ----------------
  if (tid < 64) {
    float md[16];
#pragma unroll
    for (int i = 0; i < 16; ++i) md[i] = skeys[tid * 17 + i];
#pragma unroll 1
    for (int s = 1; s < 4; ++s) {
      int base = ((s << 6) | tid) * 17;
#pragma unroll 1
      for (int i = 0; i < 16; ++i) {
        float t = skeys[base + i];
        if (t >= md[15]) break;     // sorted: rest can't change the value-multiset
        ins16(md, t);
      }
    }
#pragma unroll
    for (int i = 0; i < 16; ++i) sbd[tid * 17 + i] = md[i];
  }
  __syncthreads();

  // ---------------- pass 2: collect candidates d <= thr ----------------
  const float thr = sbd[lane * 17 + 15];
  int cnt = 0;
  {
    float4 ld = pk[j0 + lane];
    for (int t = 0; t < 16; ++t) {
      const int buf = t & 1;
      tiles[wv][buf][lane] = ld;
      if (t < 15) ld = pk[j0 + ((t + 1) << 6) + lane];
#pragma unroll 4
      for (int j = 0; j < 64; ++j) {
        float d = distf(qx, qy, qz, qq, tiles[wv][buf][j]);
        if (d <= thr && cnt < 16) {
          cand[wv][cnt][lane] = make_uint2(__float_as_uint(d), (unsigned)(j0 + (t << 6) + j));
          ++cnt;
        }
      }
    }
  }
  ccnt[wv][lane] = cnt;
  __syncthreads();

  // ---------------- pass 3: exact rank placement (wave 0) ----------------
  if (tid < 64) {
    float md[16];
#pragma unroll
    for (int i = 0; i < 16; ++i) md[i] = sbd[tid * 17 + i];
    int cn[4];
#pragma unroll
    for (int s = 0; s < 4; ++s) cn[s] = ccnt[s][tid];
    const int ob = ((((b << 12) | ((chunk << 6) | tid))) << 5) + (set << 4);
#pragma unroll 1
    for (int s = 0; s < 4; ++s) {
#pragma unroll 1
      for (int i = 0; i < cn[s]; ++i) {
        uint2 u = cand[s][i][tid];
        float dv = __uint_as_float(u.x);
        int r = 0;
#pragma unroll
        for (int j = 0; j < 16; ++j) r += (md[j] < dv) ? 1 : 0;
        // count earlier-index candidates with bitwise-equal d (exact tie-break)
        int teq = 0;
#pragma unroll 1
        for (int s2 = 0; s2 <= s; ++s2) {
          int lim = (s2 == s) ? i : cn[s2];
#pragma unroll 1
          for (int i2 = 0; i2 < lim; ++i2) teq += (cand[s2][i2][tid].x == u.x) ? 1 : 0;
        }
        int rr = r + teq;
        if (rr < 16) idx_out[ob + rr] = (int)u.y;
      }
    }
  }
}

// grid: 2048 blocks x 256; thread = (b, n, kk); weights in LDS (broadcast reads),
// packed-fp32 (v_pk_fma_f32) MLP.
__global__ __launch_bounds__(256) void fusion_kernel(const float* __restrict__ p1,
                                                     const float* __restrict__ wts,
                                                     const float4* __restrict__ pkall,
                                                     const int* __restrict__ knn_idx,
                                                     float* __restrict__ out) {
  __shared__ __align__(16) float w[NWTS];   // 50 KB: all fused weights
  for (int i = threadIdx.x; i < NWTS / 4; i += 256)
    ((float4*)w)[i] = ((const float4*)wts)[i];
  __syncthreads();

  const int pos = blockIdx.x * 256 + threadIdx.x;
  const int kk = pos & 31;
  const int n = (pos >> 5) & (NN - 1);
  const int b = pos >> 17;

  const float qx = p1[(b * 3 + 0) * NN + n];
  const float qy = p1[(b * 3 + 1) * NN + n];
  const float qz = p1[(b * 3 + 2) * NN + n];

  const int set = kk >> 4;
  const int id = knn_idx[(((b << 12) | n) << 5) | kk];
  const float4 rv = pkall[(size_t)(set * BB + b) * NN + id];

  const float rx = rv.x - qx, ry = rv.y - qy, rz = rv.z - qz;
  const float sq = rx * rx + ry * ry + rz * rz;
  const float dist = sqrtf(fmaxf(sq, 1e-12f));

  // layers 0+1: h0[c] recomputed per c; h1 packed as 32 x float2
  v2f h1v[32];
#pragma unroll
  for (int j = 0; j < 32; ++j) h1v[j] = mkv2(0.f, 0.f);

#pragma unroll 4
  for (int c = 0; c < 64; ++c) {
    float4 m = ((const float4*)(w + OFF_W0S))[c];
    float h0 = fmaf(m.x, rx, fmaf(m.y, ry, fmaf(m.z, rz, fmaf(m.w, dist, w[OFF_B0F + c]))));
    h0 = fmaxf(h0, 0.f);
    v2f h0v = mkv2(h0, h0);
    const float4* w4 = (const float4*)(w + OFF_W1T + (c << 6));
#pragma unroll
    for (int q = 0; q < 16; ++q) {
      float4 ww = w4[q];
      h1v[2 * q]     = vfma2(mkv2(ww.x, ww.y), h0v, h1v[2 * q]);
      h1v[2 * q + 1] = vfma2(mkv2(ww.z, ww.w), h0v, h1v[2 * q + 1]);
    }
  }
  {
    const float4* b14 = (const float4*)(w + OFF_B1);
#pragma unroll
    for (int q = 0; q < 16; ++q) {
      float4 bb = b14[q];
      h1v[2 * q]     = vmax2(h1v[2 * q] + mkv2(bb.x, bb.y), mkv2(0.f, 0.f));
      h1v[2 * q + 1] = vmax2(h1v[2 * q + 1] + mkv2(bb.z, bb.w), mkv2(0.f, 0.f));
    }
  }

  // layer 2: only channel max needed
  float mx = -INFINITY;
#pragma unroll 2
  for (int o = 0; o < 128; ++o) {
    const float4* w4 = (const float4*)(w + OFF_W2 + (o << 6));
    v2f accA = mkv2(w[OFF_B2 + o], 0.f);
    v2f accB = mkv2(0.f, 0.f);
#pragma unroll
    for (int q = 0; q < 16; q += 2) {
      float4 wa = w4[q];
      accA = vfma2(mkv2(wa.x, wa.y), h1v[2 * q], accA);
      accB = vfma2(mkv2(wa.z, wa.w), h1v[2 * q + 1], accB);
      float4 wb = w4[q + 1];
      accA = vfma2(mkv2(wb.x, wb.y), h1v[2 * q + 2], accA);
      accB = vfma2(mkv2(wb.z, wb.w), h1v[2 * q + 3], accB);
    }
    float s = (accA.x + accA.y) + (accB.x + accB.y);
    mx = fmaxf(mx, s);
  }
  mx = fmaxf(mx, 0.f);  // relu commutes with channel-max

  // softmax over 32 kk lanes + weighted sum of neighbor coords
  float gm = mx;
#pragma unroll
  for (int off = 16; off > 0; off >>= 1) gm = fmaxf(gm, __shfl_xor(gm, off));
  float e = __expf(mx - gm);
  float es = e, ex = e * rv.x, ey = e * rv.y, ez = e * rv.z;
#pragma unroll
  for (int off = 16; off > 0; off >>= 1) {
    es += __shfl_xor(es, off);
    ex += __shfl_xor(ex, off);
    ey += __shfl_xor(ey, off);
    ez += __shfl_xor(ez, off);
  }
  if (kk == 0) {
    float inv = 1.f / es;
    out[(b * 3 + 0) * NN + n] = ex * inv;
    out[(b * 3 + 1) * NN + n] = ey * inv;
    out[(b * 3 + 2) * NN + n] = ez * inv;
  }
}

extern "C" void kernel_launch(void* const* d_in, const int* in_sizes, int n_in,
                              void* d_out, int out_size, void* d_ws, size_t ws_size,
                              hipStream_t stream) {
  const float* p1 = (const float*)d_in[0];
  const float* p2 = (const float*)d_in[1];
  float* ws = (float*)d_ws;
  float* out = (float*)d_out;

  prep_kernel<<<128, 256, 0, stream>>>(
      p1, p2,
      (const float*)d_in[3],  (const float*)d_in[4],  (const float*)d_in[5],
      (const float*)d_in[6],  (const float*)d_in[7],  (const float*)d_in[8],
      (const float*)d_in[9],  (const float*)d_in[10], (const float*)d_in[11],
      (const float*)d_in[12], (const float*)d_in[13], (const float*)d_in[14],
      (const float*)d_in[15], (const float*)d_in[16], (const float*)d_in[17],
      (const float*)d_in[18], (const float*)d_in[19], (const float*)d_in[20],
      ws);
  knn_kernel<<<512, 256, 0, stream>>>(p1, (const float4*)(ws + OFF_PACK),
                                      (int*)(ws + OFF_IDX));
  fusion_kernel<<<2048, 256, 0, stream>>>(p1, ws, (const float4*)(ws + OFF_PACK),
                                          (const int*)(ws + OFF_IDX), out);
}

// Round 6
// 438.752 us; speedup vs baseline: 1.4998x; 1.4998x over previous
//
#include <hip/hip_runtime.h>
#include <math.h>

#define BB 4
#define NN 4096

// workspace layout (float offsets)
#define OFF_W0S   0        // 256 fp32: w0*s0 [c][4]
#define OFF_B0F   256      // 64 fp32
#define OFF_B1    320      // 64 fp32
#define OFF_B2    384      // 128 fp32
#define OFF_W1F   512      // 4096 bf16 (2048 floats): W1 B-frags [kb*4+nb][lane][8]
#define OFF_W2F   2560     // 8192 bf16 (4096 floats): W2 A-frags [mb*2+kb][lane][8]
#define OFF_PACK  6656     // float4 refs [set][b][j] = (x,y,z,|r|^2) (131072 floats)
#define OFF_IDX   137728   // int knn idx [b][n][32] (524288 ints)

typedef __attribute__((ext_vector_type(8))) short bf16x8;
typedef __attribute__((ext_vector_type(4))) float f32x4;

static __device__ __forceinline__ unsigned short f2bf(float f) {  // RNE
  unsigned u = __float_as_uint(f);
  unsigned r = u + 0x7FFFu + ((u >> 16) & 1u);
  return (unsigned short)(r >> 16);
}

__global__ __launch_bounds__(256) void prep_kernel(
    const float* __restrict__ p1, const float* __restrict__ p2,
    const float* __restrict__ w0, const float* __restrict__ b0, const float* __restrict__ g0,
    const float* __restrict__ be0, const float* __restrict__ m0, const float* __restrict__ v0,
    const float* __restrict__ w1, const float* __restrict__ b1, const float* __restrict__ g1,
    const float* __restrict__ be1, const float* __restrict__ m1, const float* __restrict__ v1,
    const float* __restrict__ w2, const float* __restrict__ b2, const float* __restrict__ g2,
    const float* __restrict__ be2, const float* __restrict__ m2, const float* __restrict__ v2,
    float* __restrict__ ws) {
  int gid = blockIdx.x * 256 + threadIdx.x;
  if (gid < 2 * BB * NN) {   // pack refs with |r|^2
    int set = gid >> 14;
    int rem = gid & (BB * NN - 1);
    int b = rem >> 12, j = rem & (NN - 1);
    const float* p = set ? p2 : p1;
    float x = p[(b * 3 + 0) * NN + j];
    float y = p[(b * 3 + 1) * NN + j];
    float z = p[(b * 3 + 2) * NN + j];
    ((float4*)(ws + OFF_PACK))[gid] = make_float4(x, y, z, x * x + y * y + z * z);
  }
  if (gid < 256) {                         // W0S[c][4] fp32
    int c = gid >> 2, f = gid & 3;
    float s = g0[c] / sqrtf(v0[c] + 1e-3f);
    ws[OFF_W0S + gid] = w0[c * 4 + f] * s;
  } else if (gid < 320) {                  // B0F
    int c = gid - 256;
    float s = g0[c] / sqrtf(v0[c] + 1e-3f);
    ws[OFF_B0F + c] = (b0[c] - m0[c]) * s + be0[c];
  } else if (gid < 384) {                  // B1
    int o = gid - 320;
    float s = g1[o] / sqrtf(v1[o] + 1e-3f);
    ws[OFF_B1 + o] = (b1[o] - m1[o]) * s + be1[o];
  } else if (gid < 512) {                  // B2
    int o = gid - 384;
    float s = g2[o] / sqrtf(v2[o] + 1e-3f);
    ws[OFF_B2 + o] = (b2[o] - m2[o]) * s + be2[o];
  } else if (gid < 4608) {                 // W1 B-frags bf16: B[k=c][n=o]
    int e = gid - 512;
    int f = e >> 9, rem = e & 511, l = rem >> 3, j = rem & 7;
    int nb = f & 3, kb = f >> 2;
    int o = nb * 16 + (l & 15);
    int c = kb * 32 + (l >> 4) * 8 + j;
    float s = g1[o] / sqrtf(v1[o] + 1e-3f);
    ((unsigned short*)ws)[OFF_W1F * 2 + e] = f2bf(w1[o * 64 + c] * s);
  } else if (gid < 12800) {                // W2 A-frags bf16: A[m=o][k=c]
    int e = gid - 4608;
    int f = e >> 9, rem = e & 511, l = rem >> 3, j = rem & 7;
    int mb = f >> 1, kb = f & 1;
    int o = mb * 16 + (l & 15);
    int c = kb * 32 + (l >> 4) * 8 + j;
    float s = g2[o] / sqrtf(v2[o] + 1e-3f);
    ((unsigned short*)ws)[OFF_W2F * 2 + e] = f2bf(w2[o * 64 + c] * s);
  }
}

__device__ __forceinline__ float distf(float qx, float qy, float qz, float qq,
                                       const float4& rv) {
  // pinned op order: bitwise-identical d in every pass
  float dt = fmaf(qx, rv.x, fmaf(qy, rv.y, qz * rv.z));
  return fmaxf(fmaf(-2.f, dt, qq + rv.w), 0.f);
}

__device__ __forceinline__ void ins16(float (&bd)[16], float t) {
#pragma unroll
  for (int i = 0; i < 16; ++i) { float lo = fminf(t, bd[i]); t = fmaxf(t, bd[i]); bd[i] = lo; }
}

__device__ __forceinline__ void argmin8(const float (&d)[8], float& m, int& mi) {
  float ma = fminf(d[0], d[1]); int ia = (d[1] < d[0]) ? 1 : 0;
  float mb = fminf(d[2], d[3]); int ib = (d[3] < d[2]) ? 3 : 2;
  float mc = fminf(d[4], d[5]); int ic = (d[5] < d[4]) ? 5 : 4;
  float md = fminf(d[6], d[7]); int id = (d[7] < d[6]) ? 7 : 6;
  float me = fminf(ma, mb);     int ie = (mb < ma) ? ib : ia;
  float mf = fminf(mc, md);     int ig = (md < mc) ? id : ic;
  m = fminf(me, mf);            mi = (mf < me) ? ig : ie;
}

// grid: 512 blocks (set|chunk|b) x 256 (4 ref-split waves x 64 queries).
// Refs read via wave-uniform global loads (scalar path). Pass1 keys-only,
// merge -> exact top-16 values, pass2 rescans and writes final ranks to global.
__global__ __launch_bounds__(256) void knn_kernel(const float* __restrict__ p1,
                                                  const float4* __restrict__ pkall,
                                                  int* __restrict__ idx_out) {
  __shared__ float skeys[256 * 17];   // per-thread sorted keys (pad 17: 2-way free)
  __shared__ float sbd[64 * 17];      // merged top-16 per query
  __shared__ int dup[64][16];         // bitwise-dup slot counters (rare path)

  const int tid = threadIdx.x;
  const int lane = tid & 63;
  const int wv = tid >> 6;
  const int set = blockIdx.x & 1;
  const int chunk = (blockIdx.x >> 1) & 63;
  const int b = blockIdx.x >> 7;
  const int n = (chunk << 6) | lane;

  const float qx = p1[(b * 3 + 0) * NN + n];
  const float qy = p1[(b * 3 + 1) * NN + n];
  const float qz = p1[(b * 3 + 2) * NN + n];
  const float qq = qx * qx + qy * qy + qz * qz;

  const float4* __restrict__ pk = pkall + (size_t)(set * BB + b) * NN;
  const int j0 = wv << 10;

  // ---- pass 1: exact top-16 distance values for this split ----
  float bd[16];
#pragma unroll
  for (int i = 0; i < 16; ++i) bd[i] = INFINITY;
  float worst = INFINITY;

  for (int jb = j0; jb < j0 + 1024; jb += 8) {
    float d[8];
#pragma unroll
    for (int r = 0; r < 8; ++r) d[r] = distf(qx, qy, qz, qq, pk[jb + r]);
    float m; int mi;
    argmin8(d, m, mi);
    if (m < worst) {
      ins16(bd, m); worst = bd[15];
#pragma unroll
      for (int r = 0; r < 8; ++r) {
        if (r != mi && d[r] < worst) { ins16(bd, d[r]); worst = bd[15]; }
      }
    }
  }

#pragma unroll
  for (int i = 0; i < 16; ++i) skeys[tid * 17 + i] = bd[i];
  for (int i = tid; i < 64 * 16; i += 256) ((int*)dup)[i] = 0;
  __syncthreads();

  // ---- merge 4 sorted lists -> exact global top-16 values (wave 0) ----
  if (tid < 64) {
    float md[16];
#pragma unroll
    for (int i = 0; i < 16; ++i) md[i] = skeys[tid * 17 + i];
#pragma unroll 1
    for (int s = 1; s < 4; ++s) {
      int base = ((s << 6) | tid) * 17;
#pragma unroll 1
      for (int i = 0; i < 16; ++i) {
        float t = skeys[base + i];
        if (t >= md[15]) break;   // sorted: rest can't qualify
        ins16(md, t);
      }
    }
#pragma unroll
    for (int i = 0; i < 16; ++i) sbd[tid * 17 + i] = md[i];
  }
  __syncthreads();

  // ---- pass 2: rescan, place candidates at their exact rank ----
  float mbd[16];
#pragma unroll
  for (int i = 0; i < 16; ++i) mbd[i] = sbd[lane * 17 + i];
  const float thr = mbd[15];
  const int ob = (((b << 12) | n) << 5) + (set << 4);

  for (int jb = j0; jb < j0 + 1024; jb += 8) {
    float d[8];
#pragma unroll
    for (int r = 0; r < 8; ++r) d[r] = distf(qx, qy, qz, qq, pk[jb + r]);
    float m = fminf(fminf(fminf(d[0], d[1]), fminf(d[2], d[3])),
                    fminf(fminf(d[4], d[5]), fminf(d[6], d[7])));
    if (m <= thr) {
#pragma unroll
      for (int r = 0; r < 8; ++r) {
        if (d[r] <= thr) {
          int r0 = 0, ne = 0;
#pragma unroll
          for (int j = 0; j < 16; ++j) {
            r0 += (mbd[j] < d[r]) ? 1 : 0;
            ne += (mbd[j] == d[r]) ? 1 : 0;
          }
          int slot = r0;
          if (ne > 1) slot = r0 + atomicAdd(&dup[lane][r0], 1);  // bitwise-dup: ~never
          if (slot < 16) idx_out[ob + slot] = jb + r;
        }
      }
    }
  }
}

// grid: 4096 blocks x 256 (4 waves); wave = 1 query x 32 kk positions.
// Layer0 fp32 VALU -> bf16 -> LDS transpose; layers 1&2 on MFMA bf16.
__global__ __launch_bounds__(256) void fusion_kernel(
    const float* __restrict__ p1, const float* __restrict__ ws,
    const float4* __restrict__ pkall, const int* __restrict__ knn_idx,
    float* __restrict__ out) {
  __shared__ __align__(16) unsigned short hbuf[4][32][72];  // [wave][pos][ch] bf16
  __shared__ float sscore[4][32];

  const int tid = threadIdx.x;
  const int l = tid & 63;
  const int wv = tid >> 6;
  const int wid = blockIdx.x * 4 + wv;     // 0..16383
  const int pbase = wid << 5;
  const int b = pbase >> 17;
  const int n = (pbase >> 5) & (NN - 1);
  const int kk = l & 31;
  const int half = l >> 5;

  // wave-uniform query
  const float qx = p1[(b * 3 + 0) * NN + n];
  const float qy = p1[(b * 3 + 1) * NN + n];
  const float qz = p1[(b * 3 + 2) * NN + n];

  // neighbor of position kk ( & (NN-1): defensive clamp, no-op when knn is correct )
  const int set = kk >> 4;
  const int id = knn_idx[pbase + kk] & (NN - 1);
  const float4 rv = pkall[(size_t)(set * BB + b) * NN + id];
  const float rx = rv.x - qx, ry = rv.y - qy, rz = rv.z - qz;
  const float dist = sqrtf(fmaxf(rx * rx + ry * ry + rz * rz, 1e-12f));

  // resident W1 B-frags (8 x 16B, coalesced, L1-hot)
  const bf16x8* w1f = (const bf16x8*)(ws + OFF_W1F);
  bf16x8 w1r[8];
#pragma unroll
  for (int f = 0; f < 8; ++f) w1r[f] = w1f[f * 64 + l];

  // ---- layer 0 (fp32 VALU): this lane computes 32 of 64 channels ----
  // R5 bug fixed here: 32 channels = 16 packed uints = FOUR uint4 stores
  // (previously only 2 were stored -> half of hbuf stale -> inf -> NaN).
  {
    const int cb = half * 32;
    const float4* w0 = (const float4*)(ws + OFF_W0S);
    float b0v[32];
#pragma unroll
    for (int q = 0; q < 8; ++q) {
      float4 bb = ((const float4*)(ws + OFF_B0F))[half * 8 + q];
      b0v[4 * q] = bb.x; b0v[4 * q + 1] = bb.y; b0v[4 * q + 2] = bb.z; b0v[4 * q + 3] = bb.w;
    }
    unsigned pk2[16];
#pragma unroll
    for (int i = 0; i < 32; i += 2) {
      float4 wa = w0[cb + i], wb = w0[cb + i + 1];
      float ha = fmaxf(fmaf(wa.x, rx, fmaf(wa.y, ry, fmaf(wa.z, rz, fmaf(wa.w, dist, b0v[i])))), 0.f);
      float hb = fmaxf(fmaf(wb.x, rx, fmaf(wb.y, ry, fmaf(wb.z, rz, fmaf(wb.w, dist, b0v[i + 1])))), 0.f);
      pk2[i >> 1] = ((unsigned)f2bf(hb) << 16) | (unsigned)f2bf(ha);
    }
    uint4* dst = (uint4*)&hbuf[wv][kk][cb];
    dst[0] = make_uint4(pk2[0], pk2[1], pk2[2], pk2[3]);
    dst[1] = make_uint4(pk2[4], pk2[5], pk2[6], pk2[7]);
    dst[2] = make_uint4(pk2[8], pk2[9], pk2[10], pk2[11]);
    dst[3] = make_uint4(pk2[12], pk2[13], pk2[14], pk2[15]);
  }
  __syncthreads();   // fence 1: h0 writes -> A-frag reads

  // ---- layer 1: D[pos][o] = h0 . W1 (MFMA), C init = bias1[col] ----
  f32x4 c1[2][4];
  {
    float b1v[4];
#pragma unroll
    for (int nb = 0; nb < 4; ++nb) b1v[nb] = ws[OFF_B1 + nb * 16 + (l & 15)];
#pragma unroll
    for (int mb = 0; mb < 2; ++mb)
#pragma unroll
      for (int nb = 0; nb < 4; ++nb) {
        c1[mb][nb][0] = b1v[nb]; c1[mb][nb][1] = b1v[nb];
        c1[mb][nb][2] = b1v[nb]; c1[mb][nb][3] = b1v[nb];
      }
  }
  bf16x8 a1[2][2];
#pragma unroll
  for (int mb = 0; mb < 2; ++mb)
#pragma unroll
    for (int kb = 0; kb < 2; ++kb)
      a1[mb][kb] = *(const bf16x8*)&hbuf[wv][mb * 16 + (l & 15)][kb * 32 + (l >> 4) * 8];
#pragma unroll
  for (int mb = 0; mb < 2; ++mb)
#pragma unroll
    for (int nb = 0; nb < 4; ++nb)
#pragma unroll
      for (int kb = 0; kb < 2; ++kb)
        c1[mb][nb] = __builtin_amdgcn_mfma_f32_16x16x32_bf16(a1[mb][kb], w1r[kb * 4 + nb],
                                                             c1[mb][nb], 0, 0, 0);

  // epilogue: relu -> bf16 -> scatter back into hbuf (h1, same [pos][ch] layout)
#pragma unroll
  for (int mb = 0; mb < 2; ++mb)
#pragma unroll
    for (int nb = 0; nb < 4; ++nb) {
      const int ch = nb * 16 + (l & 15);
#pragma unroll
      for (int r = 0; r < 4; ++r) {
        float h = fmaxf(c1[mb][nb][r], 0.f);
        hbuf[wv][mb * 16 + (l >> 4) * 4 + r][ch] = f2bf(h);
      }
    }
  __syncthreads();   // fence 2: h1 writes -> B-frag reads

  // ---- layer 2: D2^T = W2 . h1^T, bias-as-C-init, running channel max ----
  bf16x8 b2f[2][2];
#pragma unroll
  for (int nb = 0; nb < 2; ++nb)
#pragma unroll
    for (int kb = 0; kb < 2; ++kb)
      b2f[nb][kb] = *(const bf16x8*)&hbuf[wv][nb * 16 + (l & 15)][kb * 32 + (l >> 4) * 8];

  const bf16x8* w2f = (const bf16x8*)(ws + OFF_W2F);
  f32x4 rmax[2];
  rmax[0][0] = rmax[0][1] = rmax[0][2] = rmax[0][3] = -INFINITY;
  rmax[1] = rmax[0];
#pragma unroll
  for (int mb = 0; mb < 8; ++mb) {
    bf16x8 a0 = w2f[(mb * 2 + 0) * 64 + l];
    bf16x8 a1_ = w2f[(mb * 2 + 1) * 64 + l];
    float4 bb = ((const float4*)(ws + OFF_B2))[mb * 4 + (l >> 4)];
    f32x4 cini; cini[0] = bb.x; cini[1] = bb.y; cini[2] = bb.z; cini[3] = bb.w;
#pragma unroll
    for (int nb = 0; nb < 2; ++nb) {
      f32x4 c = __builtin_amdgcn_mfma_f32_16x16x32_bf16(a0, b2f[nb][0], cini, 0, 0, 0);
      c = __builtin_amdgcn_mfma_f32_16x16x32_bf16(a1_, b2f[nb][1], c, 0, 0, 0);
#pragma unroll
      for (int r = 0; r < 4; ++r) rmax[nb][r] = fmaxf(rmax[nb][r], c[r]);
    }
  }

  // reduce rows (channels) -> score per position; relu commutes with max
#pragma unroll
  for (int nb = 0; nb < 2; ++nb) {
    float m = fmaxf(fmaxf(rmax[nb][0], rmax[nb][1]), fmaxf(rmax[nb][2], rmax[nb][3]));
    m = fmaxf(m, __shfl_xor(m, 16));
    m = fmaxf(m, __shfl_xor(m, 32));
    m = fmaxf(m, 0.f);
    if ((l >> 4) == 0) sscore[wv][nb * 16 + l] = m;
  }
  __syncthreads();   // fence 3: score writes -> score reads

  // ---- softmax over 32 kk + weighted sum of neighbor coords ----
  // (both 32-lane halves hold identical kk sets: the doubled sums cancel in ratio)
  float sc = sscore[wv][kk];
  float gm = sc;
#pragma unroll
  for (int off = 16; off > 0; off >>= 1) gm = fmaxf(gm, __shfl_xor(gm, off));
  float e = __expf(sc - gm);
  float es = e, ex = e * rv.x, ey = e * rv.y, ez = e * rv.z;
#pragma unroll
  for (int off = 16; off > 0; off >>= 1) {
    es += __shfl_xor(es, off);
    ex += __shfl_xor(ex, off);
    ey += __shfl_xor(ey, off);
    ez += __shfl_xor(ez, off);
  }
  if (l == 0) {
    float inv = 1.f / es;
    out[(b * 3 + 0) * NN + n] = ex * inv;
    out[(b * 3 + 1) * NN + n] = ey * inv;
    out[(b * 3 + 2) * NN + n] = ez * inv;
  }
}

extern "C" void kernel_launch(void* const* d_in, const int* in_sizes, int n_in,
                              void* d_out, int out_size, void* d_ws, size_t ws_size,
                              hipStream_t stream) {
  const float* p1 = (const float*)d_in[0];
  const float* p2 = (const float*)d_in[1];
  float* ws = (float*)d_ws;
  float* out = (float*)d_out;

  prep_kernel<<<128, 256, 0, stream>>>(
      p1, p2,
      (const float*)d_in[3],  (const float*)d_in[4],  (const float*)d_in[5],
      (const float*)d_in[6],  (const float*)d_in[7],  (const float*)d_in[8],
      (const float*)d_in[9],  (const float*)d_in[10], (const float*)d_in[11],
      (const float*)d_in[12], (const float*)d_in[13], (const float*)d_in[14],
      (const float*)d_in[15], (const float*)d_in[16], (const float*)d_in[17],
      (const float*)d_in[18], (const float*)d_in[19], (const float*)d_in[20],
      ws);
  knn_kernel<<<512, 256, 0, stream>>>(p1, (const float4*)(ws + OFF_PACK),
                                      (int*)(ws + OFF_IDX));
  fusion_kernel<<<4096, 256, 0, stream>>>(p1, ws, (const float4*)(ws + OFF_PACK),
                                          (const int*)(ws + OFF_IDX), out);
}

// Round 7
// 417.362 us; speedup vs baseline: 1.5767x; 1.0512x over previous
//
#include <hip/hip_runtime.h>
#include <math.h>

#define BB 4
#define NN 4096

// workspace layout (float offsets)
#define OFF_W0S   0        // 256 fp32: w0*s0 [c][4]
#define OFF_B0F   256      // 64 fp32
#define OFF_B1    320      // 64 fp32
#define OFF_B2    384      // 128 fp32
#define OFF_W1F   512      // 4096 bf16 (2048 floats): W1 B-frags [kb*4+nb][lane][8]
#define OFF_W2F   2560     // 8192 bf16 (4096 floats): W2 A-frags [mb*2+kb][lane][8]
#define OFF_PACK  6656     // float4 refs [set][b][j] = (x,y,z,|r|^2) (131072 floats)
#define OFF_IDX   137728   // int knn idx [b][n][32] (524288 ints)

typedef __attribute__((ext_vector_type(8))) short bf16x8;
typedef __attribute__((ext_vector_type(4))) float f32x4;

static __device__ __forceinline__ unsigned short f2bf(float f) {  // RNE
  unsigned u = __float_as_uint(f);
  unsigned r = u + 0x7FFFu + ((u >> 16) & 1u);
  return (unsigned short)(r >> 16);
}

__global__ __launch_bounds__(256) void prep_kernel(
    const float* __restrict__ p1, const float* __restrict__ p2,
    const float* __restrict__ w0, const float* __restrict__ b0, const float* __restrict__ g0,
    const float* __restrict__ be0, const float* __restrict__ m0, const float* __restrict__ v0,
    const float* __restrict__ w1, const float* __restrict__ b1, const float* __restrict__ g1,
    const float* __restrict__ be1, const float* __restrict__ m1, const float* __restrict__ v1,
    const float* __restrict__ w2, const float* __restrict__ b2, const float* __restrict__ g2,
    const float* __restrict__ be2, const float* __restrict__ m2, const float* __restrict__ v2,
    float* __restrict__ ws) {
  int gid = blockIdx.x * 256 + threadIdx.x;
  if (gid < 2 * BB * NN) {   // pack refs with |r|^2
    int set = gid >> 14;
    int rem = gid & (BB * NN - 1);
    int b = rem >> 12, j = rem & (NN - 1);
    const float* p = set ? p2 : p1;
    float x = p[(b * 3 + 0) * NN + j];
    float y = p[(b * 3 + 1) * NN + j];
    float z = p[(b * 3 + 2) * NN + j];
    ((float4*)(ws + OFF_PACK))[gid] = make_float4(x, y, z, x * x + y * y + z * z);
  }
  if (gid < 256) {                         // W0S[c][4] fp32
    int c = gid >> 2, f = gid & 3;
    float s = g0[c] / sqrtf(v0[c] + 1e-3f);
    ws[OFF_W0S + gid] = w0[c * 4 + f] * s;
  } else if (gid < 320) {                  // B0F
    int c = gid - 256;
    float s = g0[c] / sqrtf(v0[c] + 1e-3f);
    ws[OFF_B0F + c] = (b0[c] - m0[c]) * s + be0[c];
  } else if (gid < 384) {                  // B1
    int o = gid - 320;
    float s = g1[o] / sqrtf(v1[o] + 1e-3f);
    ws[OFF_B1 + o] = (b1[o] - m1[o]) * s + be1[o];
  } else if (gid < 512) {                  // B2
    int o = gid - 384;
    float s = g2[o] / sqrtf(v2[o] + 1e-3f);
    ws[OFF_B2 + o] = (b2[o] - m2[o]) * s + be2[o];
  } else if (gid < 4608) {                 // W1 B-frags bf16: B[k=c][n=o]
    int e = gid - 512;
    int f = e >> 9, rem = e & 511, l = rem >> 3, j = rem & 7;
    int nb = f & 3, kb = f >> 2;
    int o = nb * 16 + (l & 15);
    int c = kb * 32 + (l >> 4) * 8 + j;
    float s = g1[o] / sqrtf(v1[o] + 1e-3f);
    ((unsigned short*)ws)[OFF_W1F * 2 + e] = f2bf(w1[o * 64 + c] * s);
  } else if (gid < 12800) {                // W2 A-frags bf16: A[m=o][k=c]
    int e = gid - 4608;
    int f = e >> 9, rem = e & 511, l = rem >> 3, j = rem & 7;
    int mb = f >> 1, kb = f & 1;
    int o = mb * 16 + (l & 15);
    int c = kb * 32 + (l >> 4) * 8 + j;
    float s = g2[o] / sqrtf(v2[o] + 1e-3f);
    ((unsigned short*)ws)[OFF_W2F * 2 + e] = f2bf(w2[o * 64 + c] * s);
  }
}

__device__ __forceinline__ float distf(float qx, float qy, float qz, float qq,
                                       const float4& rv) {
  // pinned op order: bitwise-identical d in every pass
  float dt = fmaf(qx, rv.x, fmaf(qy, rv.y, qz * rv.z));
  return fmaxf(fmaf(-2.f, dt, qq + rv.w), 0.f);
}

__device__ __forceinline__ void ins16(float (&bd)[16], float t) {
#pragma unroll
  for (int i = 0; i < 16; ++i) { float lo = fminf(t, bd[i]); t = fmaxf(t, bd[i]); bd[i] = lo; }
}

__device__ __forceinline__ void argmin8(const float (&d)[8], float& m, int& mi) {
  float ma = fminf(d[0], d[1]); int ia = (d[1] < d[0]) ? 1 : 0;
  float mb = fminf(d[2], d[3]); int ib = (d[3] < d[2]) ? 3 : 2;
  float mc = fminf(d[4], d[5]); int ic = (d[5] < d[4]) ? 5 : 4;
  float md = fminf(d[6], d[7]); int id = (d[7] < d[6]) ? 7 : 6;
  float me = fminf(ma, mb);     int ie = (mb < ma) ? ib : ia;
  float mf = fminf(mc, md);     int ig = (md < mc) ? id : ic;
  m = fminf(me, mf);            mi = (mf < me) ? ig : ie;
}

// grid: 512 blocks (set|chunk|b) x 512 threads (8 ref-split waves x 64 queries).
// wv is readfirstlane'd -> ref addresses provably wave-uniform -> scalar loads.
// Pass1 keys-only top-16/split, merge -> exact top-16 values, pass2 rescans and
// writes final ranks straight to global (no LDS candidate arrays).
__global__ __launch_bounds__(512) void knn_kernel(const float* __restrict__ p1,
                                                  const float4* __restrict__ pkall,
                                                  int* __restrict__ idx_out) {
  __shared__ float skeys[512 * 17];   // per-thread sorted keys (pad 17)
  __shared__ float sbd[64 * 17];      // merged top-16 per query
  __shared__ int dup[64][16];         // bitwise-dup slot counters (rare path)

  const int tid = threadIdx.x;
  const int lane = tid & 63;
  const int wv = __builtin_amdgcn_readfirstlane(tid >> 6);  // split 0..7, SGPR
  const int set = blockIdx.x & 1;
  const int chunk = (blockIdx.x >> 1) & 63;
  const int b = blockIdx.x >> 7;
  const int n = (chunk << 6) | lane;

  const float qx = p1[(b * 3 + 0) * NN + n];
  const float qy = p1[(b * 3 + 1) * NN + n];
  const float qz = p1[(b * 3 + 2) * NN + n];
  const float qq = qx * qx + qy * qy + qz * qz;

  const float4* __restrict__ pk = pkall + (size_t)(set * BB + b) * NN;
  const int j0 = wv << 9;             // 512 refs per split

  // ---- pass 1: exact top-16 distance values for this split ----
  float bd[16];
#pragma unroll
  for (int i = 0; i < 16; ++i) bd[i] = INFINITY;
  float worst = INFINITY;

  for (int jb = j0; jb < j0 + 512; jb += 8) {
    float d[8];
#pragma unroll
    for (int r = 0; r < 8; ++r) d[r] = distf(qx, qy, qz, qq, pk[jb + r]);
    float m; int mi;
    argmin8(d, m, mi);
    if (m < worst) {
      ins16(bd, m); worst = bd[15];
#pragma unroll
      for (int r = 0; r < 8; ++r) {
        if (r != mi && d[r] < worst) { ins16(bd, d[r]); worst = bd[15]; }
      }
    }
  }

#pragma unroll
  for (int i = 0; i < 16; ++i) skeys[tid * 17 + i] = bd[i];
  for (int i = tid; i < 64 * 16; i += 512) ((int*)dup)[i] = 0;
  __syncthreads();

  // ---- merge 8 sorted lists -> exact global top-16 values (wave 0) ----
  if (tid < 64) {
    float md[16];
#pragma unroll
    for (int i = 0; i < 16; ++i) md[i] = skeys[tid * 17 + i];
#pragma unroll 1
    for (int s = 1; s < 8; ++s) {
      int base = ((s << 6) | tid) * 17;
#pragma unroll 1
      for (int i = 0; i < 16; ++i) {
        float t = skeys[base + i];
        if (t >= md[15]) break;   // sorted: rest can't qualify
        ins16(md, t);
      }
    }
#pragma unroll
    for (int i = 0; i < 16; ++i) sbd[tid * 17 + i] = md[i];
  }
  __syncthreads();

  // ---- pass 2: rescan, place candidates at their exact rank ----
  float mbd[16];
#pragma unroll
  for (int i = 0; i < 16; ++i) mbd[i] = sbd[lane * 17 + i];
  const float thr = mbd[15];
  const int ob = (((b << 12) | n) << 5) + (set << 4);

  for (int jb = j0; jb < j0 + 512; jb += 8) {
    float d[8];
#pragma unroll
    for (int r = 0; r < 8; ++r) d[r] = distf(qx, qy, qz, qq, pk[jb + r]);
    float m = fminf(fminf(fminf(d[0], d[1]), fminf(d[2], d[3])),
                    fminf(fminf(d[4], d[5]), fminf(d[6], d[7])));
    if (m <= thr) {
#pragma unroll
      for (int r = 0; r < 8; ++r) {
        if (d[r] <= thr) {
          int r0 = 0, ne = 0;
#pragma unroll
          for (int j = 0; j < 16; ++j) {
            r0 += (mbd[j] < d[r]) ? 1 : 0;
            ne += (mbd[j] == d[r]) ? 1 : 0;
          }
          int slot = r0;
          if (ne > 1) slot = r0 + atomicAdd(&dup[lane][r0], 1);  // bitwise-dup: ~never
          if (slot < 16) idx_out[ob + slot] = jb + r;
        }
      }
    }
  }
}

// grid: 4096 blocks x 256 (4 waves); wave = 1 query x 32 kk positions.
// Layer0 fp32 VALU -> bf16 -> LDS transpose; layers 1&2 on MFMA bf16.
__global__ __launch_bounds__(256) void fusion_kernel(
    const float* __restrict__ p1, const float* __restrict__ ws,
    const float4* __restrict__ pkall, const int* __restrict__ knn_idx,
    float* __restrict__ out) {
  __shared__ __align__(16) unsigned short hbuf[4][32][72];  // [wave][pos][ch] bf16
  __shared__ float sscore[4][32];

  const int tid = threadIdx.x;
  const int l = tid & 63;
  const int wv = tid >> 6;
  const int wid = blockIdx.x * 4 + wv;     // 0..16383
  const int pbase = wid << 5;
  const int b = pbase >> 17;
  const int n = (pbase >> 5) & (NN - 1);
  const int kk = l & 31;
  const int half = l >> 5;

  // wave-uniform query
  const float qx = p1[(b * 3 + 0) * NN + n];
  const float qy = p1[(b * 3 + 1) * NN + n];
  const float qz = p1[(b * 3 + 2) * NN + n];

  // neighbor of position kk ( & (NN-1): defensive clamp, no-op when knn is correct )
  const int set = kk >> 4;
  const int id = knn_idx[pbase + kk] & (NN - 1);
  const float4 rv = pkall[(size_t)(set * BB + b) * NN + id];
  const float rx = rv.x - qx, ry = rv.y - qy, rz = rv.z - qz;
  const float dist = sqrtf(fmaxf(rx * rx + ry * ry + rz * rz, 1e-12f));

  // resident W1 B-frags (8 x 16B, coalesced, L1-hot)
  const bf16x8* w1f = (const bf16x8*)(ws + OFF_W1F);
  bf16x8 w1r[8];
#pragma unroll
  for (int f = 0; f < 8; ++f) w1r[f] = w1f[f * 64 + l];

  // ---- layer 0 (fp32 VALU): this lane computes 32 of 64 channels ----
  {
    const int cb = half * 32;
    const float4* w0 = (const float4*)(ws + OFF_W0S);
    float b0v[32];
#pragma unroll
    for (int q = 0; q < 8; ++q) {
      float4 bb = ((const float4*)(ws + OFF_B0F))[half * 8 + q];
      b0v[4 * q] = bb.x; b0v[4 * q + 1] = bb.y; b0v[4 * q + 2] = bb.z; b0v[4 * q + 3] = bb.w;
    }
    unsigned pk2[16];
#pragma unroll
    for (int i = 0; i < 32; i += 2) {
      float4 wa = w0[cb + i], wb = w0[cb + i + 1];
      float ha = fmaxf(fmaf(wa.x, rx, fmaf(wa.y, ry, fmaf(wa.z, rz, fmaf(wa.w, dist, b0v[i])))), 0.f);
      float hb = fmaxf(fmaf(wb.x, rx, fmaf(wb.y, ry, fmaf(wb.z, rz, fmaf(wb.w, dist, b0v[i + 1])))), 0.f);
      pk2[i >> 1] = ((unsigned)f2bf(hb) << 16) | (unsigned)f2bf(ha);
    }
    uint4* dst = (uint4*)&hbuf[wv][kk][cb];
    dst[0] = make_uint4(pk2[0], pk2[1], pk2[2], pk2[3]);
    dst[1] = make_uint4(pk2[4], pk2[5], pk2[6], pk2[7]);
    dst[2] = make_uint4(pk2[8], pk2[9], pk2[10], pk2[11]);
    dst[3] = make_uint4(pk2[12], pk2[13], pk2[14], pk2[15]);
  }
  __syncthreads();   // fence 1: h0 writes -> A-frag reads

  // ---- layer 1: D[pos][o] = h0 . W1 (MFMA), C init = bias1[col] ----
  f32x4 c1[2][4];
  {
    float b1v[4];
#pragma unroll
    for (int nb = 0; nb < 4; ++nb) b1v[nb] = ws[OFF_B1 + nb * 16 + (l & 15)];
#pragma unroll
    for (int mb = 0; mb < 2; ++mb)
#pragma unroll
      for (int nb = 0; nb < 4; ++nb) {
        c1[mb][nb][0] = b1v[nb]; c1[mb][nb][1] = b1v[nb];
        c1[mb][nb][2] = b1v[nb]; c1[mb][nb][3] = b1v[nb];
      }
  }
  bf16x8 a1[2][2];
#pragma unroll
  for (int mb = 0; mb < 2; ++mb)
#pragma unroll
    for (int kb = 0; kb < 2; ++kb)
      a1[mb][kb] = *(const bf16x8*)&hbuf[wv][mb * 16 + (l & 15)][kb * 32 + (l >> 4) * 8];
#pragma unroll
  for (int mb = 0; mb < 2; ++mb)
#pragma unroll
    for (int nb = 0; nb < 4; ++nb)
#pragma unroll
      for (int kb = 0; kb < 2; ++kb)
        c1[mb][nb] = __builtin_amdgcn_mfma_f32_16x16x32_bf16(a1[mb][kb], w1r[kb * 4 + nb],
                                                             c1[mb][nb], 0, 0, 0);

  // epilogue: relu -> bf16 -> scatter back into hbuf (h1, same [pos][ch] layout)
#pragma unroll
  for (int mb = 0; mb < 2; ++mb)
#pragma unroll
    for (int nb = 0; nb < 4; ++nb) {
      const int ch = nb * 16 + (l & 15);
#pragma unroll
      for (int r = 0; r < 4; ++r) {
        float h = fmaxf(c1[mb][nb][r], 0.f);
        hbuf[wv][mb * 16 + (l >> 4) * 4 + r][ch] = f2bf(h);
      }
    }
  __syncthreads();   // fence 2: h1 writes -> B-frag reads

  // ---- layer 2: D2^T = W2 . h1^T, bias-as-C-init, running channel max ----
  bf16x8 b2f[2][2];
#pragma unroll
  for (int nb = 0; nb < 2; ++nb)
#pragma unroll
    for (int kb = 0; kb < 2; ++kb)
      b2f[nb][kb] = *(const bf16x8*)&hbuf[wv][nb * 16 + (l & 15)][kb * 32 + (l >> 4) * 8];

  const bf16x8* w2f = (const bf16x8*)(ws + OFF_W2F);
  f32x4 rmax[2];
  rmax[0][0] = rmax[0][1] = rmax[0][2] = rmax[0][3] = -INFINITY;
  rmax[1] = rmax[0];
#pragma unroll
  for (int mb = 0; mb < 8; ++mb) {
    bf16x8 a0 = w2f[(mb * 2 + 0) * 64 + l];
    bf16x8 a1_ = w2f[(mb * 2 + 1) * 64 + l];
    float4 bb = ((const float4*)(ws + OFF_B2))[mb * 4 + (l >> 4)];
    f32x4 cini; cini[0] = bb.x; cini[1] = bb.y; cini[2] = bb.z; cini[3] = bb.w;
#pragma unroll
    for (int nb = 0; nb < 2; ++nb) {
      f32x4 c = __builtin_amdgcn_mfma_f32_16x16x32_bf16(a0, b2f[nb][0], cini, 0, 0, 0);
      c = __builtin_amdgcn_mfma_f32_16x16x32_bf16(a1_, b2f[nb][1], c, 0, 0, 0);
#pragma unroll
      for (int r = 0; r < 4; ++r) rmax[nb][r] = fmaxf(rmax[nb][r], c[r]);
    }
  }

  // reduce rows (channels) -> score per position; relu commutes with max
#pragma unroll
  for (int nb = 0; nb < 2; ++nb) {
    float m = fmaxf(fmaxf(rmax[nb][0], rmax[nb][1]), fmaxf(rmax[nb][2], rmax[nb][3]));
    m = fmaxf(m, __shfl_xor(m, 16));
    m = fmaxf(m, __shfl_xor(m, 32));
    m = fmaxf(m, 0.f);
    if ((l >> 4) == 0) sscore[wv][nb * 16 + l] = m;
  }
  __syncthreads();   // fence 3: score writes -> score reads

  // ---- softmax over 32 kk + weighted sum of neighbor coords ----
  float sc = sscore[wv][kk];
  float gm = sc;
#pragma unroll
  for (int off = 16; off > 0; off >>= 1) gm = fmaxf(gm, __shfl_xor(gm, off));
  float e = __expf(sc - gm);
  float es = e, ex = e * rv.x, ey = e * rv.y, ez = e * rv.z;
#pragma unroll
  for (int off = 16; off > 0; off >>= 1) {
    es += __shfl_xor(es, off);
    ex += __shfl_xor(ex, off);
    ey += __shfl_xor(ey, off);
    ez += __shfl_xor(ez, off);
  }
  if (l == 0) {
    float inv = 1.f / es;
    out[(b * 3 + 0) * NN + n] = ex * inv;
    out[(b * 3 + 1) * NN + n] = ey * inv;
    out[(b * 3 + 2) * NN + n] = ez * inv;
  }
}

extern "C" void kernel_launch(void* const* d_in, const int* in_sizes, int n_in,
                              void* d_out, int out_size, void* d_ws, size_t ws_size,
                              hipStream_t stream) {
  const float* p1 = (const float*)d_in[0];
  const float* p2 = (const float*)d_in[1];
  float* ws = (float*)d_ws;
  float* out = (float*)d_out;

  prep_kernel<<<128, 256, 0, stream>>>(
      p1, p2,
      (const float*)d_in[3],  (const float*)d_in[4],  (const float*)d_in[5],
      (const float*)d_in[6],  (const float*)d_in[7],  (const float*)d_in[8],
      (const float*)d_in[9],  (const float*)d_in[10], (const float*)d_in[11],
      (const float*)d_in[12], (const float*)d_in[13], (const float*)d_in[14],
      (const float*)d_in[15], (const float*)d_in[16], (const float*)d_in[17],
      (const float*)d_in[18], (const float*)d_in[19], (const float*)d_in[20],
      ws);
  knn_kernel<<<512, 512, 0, stream>>>(p1, (const float4*)(ws + OFF_PACK),
                                      (int*)(ws + OFF_IDX));
  fusion_kernel<<<4096, 256, 0, stream>>>(p1, ws, (const float4*)(ws + OFF_PACK),
                                          (const int*)(ws + OFF_IDX), out);
}

// Round 8
// 315.116 us; speedup vs baseline: 2.0882x; 1.3245x over previous
//
#include <hip/hip_runtime.h>
#include <math.h>

#define BB 4
#define NN 4096

// workspace layout (float offsets)
#define OFF_W0S   0        // 256 fp32: w0*s0 [c][4]
#define OFF_B0F   256      // 64 fp32
#define OFF_B1    320      // 64 fp32
#define OFF_B2    384      // 128 fp32
#define OFF_W1F   512      // 4096 bf16 (2048 floats): W1 B-frags [kb*4+nb][lane][8]
#define OFF_W2F   2560     // 8192 bf16 (4096 floats): W2 A-frags [mb*2+kb][lane][8]
#define OFF_PACK  6656     // float4 refs [set][b][j] = (x,y,z,|r|^2) (131072 floats)
#define OFF_IDX   137728   // int knn idx [b][n][32] (524288 ints)

// sentinel key = key(d=+inf, idx=4095) = 0x7F800000*4096 + 4095
#define KSENT 8761733287935.0

typedef __attribute__((ext_vector_type(8))) short bf16x8;
typedef __attribute__((ext_vector_type(4))) float f32x4;

static __device__ __forceinline__ unsigned short f2bf(float f) {  // RNE
  unsigned u = __float_as_uint(f);
  unsigned r = u + 0x7FFFu + ((u >> 16) & 1u);
  return (unsigned short)(r >> 16);
}

__global__ __launch_bounds__(256) void prep_kernel(
    const float* __restrict__ p1, const float* __restrict__ p2,
    const float* __restrict__ w0, const float* __restrict__ b0, const float* __restrict__ g0,
    const float* __restrict__ be0, const float* __restrict__ m0, const float* __restrict__ v0,
    const float* __restrict__ w1, const float* __restrict__ b1, const float* __restrict__ g1,
    const float* __restrict__ be1, const float* __restrict__ m1, const float* __restrict__ v1,
    const float* __restrict__ w2, const float* __restrict__ b2, const float* __restrict__ g2,
    const float* __restrict__ be2, const float* __restrict__ m2, const float* __restrict__ v2,
    float* __restrict__ ws) {
  int gid = blockIdx.x * 256 + threadIdx.x;
  if (gid < 2 * BB * NN) {   // pack refs with |r|^2
    int set = gid >> 14;
    int rem = gid & (BB * NN - 1);
    int b = rem >> 12, j = rem & (NN - 1);
    const float* p = set ? p2 : p1;
    float x = p[(b * 3 + 0) * NN + j];
    float y = p[(b * 3 + 1) * NN + j];
    float z = p[(b * 3 + 2) * NN + j];
    ((float4*)(ws + OFF_PACK))[gid] = make_float4(x, y, z, x * x + y * y + z * z);
  }
  if (gid < 256) {                         // W0S[c][4] fp32
    int c = gid >> 2, f = gid & 3;
    float s = g0[c] / sqrtf(v0[c] + 1e-3f);
    ws[OFF_W0S + gid] = w0[c * 4 + f] * s;
  } else if (gid < 320) {                  // B0F
    int c = gid - 256;
    float s = g0[c] / sqrtf(v0[c] + 1e-3f);
    ws[OFF_B0F + c] = (b0[c] - m0[c]) * s + be0[c];
  } else if (gid < 384) {                  // B1
    int o = gid - 320;
    float s = g1[o] / sqrtf(v1[o] + 1e-3f);
    ws[OFF_B1 + o] = (b1[o] - m1[o]) * s + be1[o];
  } else if (gid < 512) {                  // B2
    int o = gid - 384;
    float s = g2[o] / sqrtf(v2[o] + 1e-3f);
    ws[OFF_B2 + o] = (b2[o] - m2[o]) * s + be2[o];
  } else if (gid < 4608) {                 // W1 B-frags bf16: B[k=c][n=o]
    int e = gid - 512;
    int f = e >> 9, rem = e & 511, l = rem >> 3, j = rem & 7;
    int nb = f & 3, kb = f >> 2;
    int o = nb * 16 + (l & 15);
    int c = kb * 32 + (l >> 4) * 8 + j;
    float s = g1[o] / sqrtf(v1[o] + 1e-3f);
    ((unsigned short*)ws)[OFF_W1F * 2 + e] = f2bf(w1[o * 64 + c] * s);
  } else if (gid < 12800) {                // W2 A-frags bf16: A[m=o][k=c]
    int e = gid - 4608;
    int f = e >> 9, rem = e & 511, l = rem >> 3, j = rem & 7;
    int mb = f >> 1, kb = f & 1;
    int o = mb * 16 + (l & 15);
    int c = kb * 32 + (l >> 4) * 8 + j;
    float s = g2[o] / sqrtf(v2[o] + 1e-3f);
    ((unsigned short*)ws)[OFF_W2F * 2 + e] = f2bf(w2[o * 64 + c] * s);
  }
}

__device__ __forceinline__ float distf(float qx, float qy, float qz, float qq,
                                       const float4& rv) {
  // pinned op order: bitwise-identical d everywhere
  float dt = fmaf(qx, rv.x, fmaf(qy, rv.y, qz * rv.z));
  return fmaxf(fmaf(-2.f, dt, qq + rv.w), 0.f);   // >=0 so d_bits is order-monotone
}

__device__ __forceinline__ void ins16d(double (&bd)[16], double t) {
#pragma unroll
  for (int i = 0; i < 16; ++i) { double lo = fmin(t, bd[i]); t = fmax(t, bd[i]); bd[i] = lo; }
}

__device__ __forceinline__ void argmin8(const float (&d)[8], float& m, int& mi) {
  float ma = fminf(d[0], d[1]); int ia = (d[1] < d[0]) ? 1 : 0;
  float mb = fminf(d[2], d[3]); int ib = (d[3] < d[2]) ? 3 : 2;
  float mc = fminf(d[4], d[5]); int ic = (d[5] < d[4]) ? 5 : 4;
  float md = fminf(d[6], d[7]); int id = (d[7] < d[6]) ? 7 : 6;
  float me = fminf(ma, mb);     int ie = (mb < ma) ? ib : ia;
  float mf = fminf(mc, md);     int ig = (md < mc) ? id : ic;
  m = fminf(me, mf);            mi = (mf < me) ? ig : ie;
}

// grid: 512 blocks (set|chunk|b) x 512 threads (8 ref-split waves x 64 queries).
// SINGLE pass: per-lane exact top-16 of 64-bit keys key = d_bits*4096 + idx
// (exact integer arithmetic in double; bit-exact d order, idx-ascending ties).
// Merge sorted lists in LDS -> write idx (= key & 4095) directly. No pass 2.
__global__ __launch_bounds__(512) void knn_kernel(const float* __restrict__ p1,
                                                  const float4* __restrict__ pkall,
                                                  int* __restrict__ idx_out) {
  __shared__ double skeys[512 * 17];   // 69.6 KB, pad 17 for bank spread

  const int tid = threadIdx.x;
  const int lane = tid & 63;
  const int wv = __builtin_amdgcn_readfirstlane(tid >> 6);  // split 0..7, SGPR
  const int set = blockIdx.x & 1;
  const int chunk = (blockIdx.x >> 1) & 63;
  const int b = blockIdx.x >> 7;
  const int n = (chunk << 6) | lane;

  const float qx = p1[(b * 3 + 0) * NN + n];
  const float qy = p1[(b * 3 + 1) * NN + n];
  const float qz = p1[(b * 3 + 2) * NN + n];
  const float qq = qx * qx + qy * qy + qz * qz;

  const float4* __restrict__ pk = pkall + (size_t)(set * BB + b) * NN;
  const int j0 = wv << 9;             // 512 refs per split

  double bd[16];
#pragma unroll
  for (int i = 0; i < 16; ++i) bd[i] = KSENT;
  float worstf = INFINITY;            // d-part of bd[15] (exact float bits)

  for (int jb = j0; jb < j0 + 512; jb += 8) {
    float d[8];
#pragma unroll
    for (int r = 0; r < 8; ++r) d[r] = distf(qx, qy, qz, qq, pk[jb + r]);
    float m; int mi;
    argmin8(d, m, mi);
    if (m <= worstf) {                // <= : equal-d lower-idx candidates qualify
      const double jbd = (double)jb;
#pragma unroll 1
      for (int it = 0; it < 8; ++it) {   // bounded: at most 8 inserts per batch
        double key = fma((double)__float_as_uint(m), 4096.0, jbd + (double)mi);
        ins16d(bd, key);
        worstf = __uint_as_float((unsigned)(bd[15] * 0x1p-12));  // trunc -> d_bits
#pragma unroll
        for (int r = 0; r < 8; ++r) d[r] = (r == mi) ? INFINITY : d[r];
        argmin8(d, m, mi);
        if (!(m <= worstf)) break;
      }
    }
  }

#pragma unroll
  for (int i = 0; i < 16; ++i) skeys[tid * 17 + i] = bd[i];
  __syncthreads();

  // ---- merge 8 sorted lists (wave 0), write final indices ----
  if (tid < 64) {
    double md[16];
#pragma unroll
    for (int i = 0; i < 16; ++i) md[i] = skeys[tid * 17 + i];
#pragma unroll 1
    for (int s = 1; s < 8; ++s) {
      int base = ((s << 6) | tid) * 17;
#pragma unroll 1
      for (int i = 0; i < 16; ++i) {
        double t = skeys[base + i];
        if (t >= md[15]) break;   // sorted: rest can't qualify
        ins16d(md, t);
      }
    }
    const int nq = (chunk << 6) | tid;
    const int ob = (((b << 12) | nq) << 5) + (set << 4);
#pragma unroll
    for (int i = 0; i < 16; ++i) {
      unsigned db = (unsigned)(md[i] * 0x1p-12);              // d_bits
      int idx = (int)(md[i] - (double)db * 4096.0);           // exact low 12 bits
      idx_out[ob + i] = idx;
    }
  }
}

// grid: 4096 blocks x 256 (4 waves); wave = 1 query x 32 kk positions.
// Layer0 fp32 VALU -> bf16 -> LDS transpose; layers 1&2 on MFMA bf16.
__global__ __launch_bounds__(256) void fusion_kernel(
    const float* __restrict__ p1, const float* __restrict__ ws,
    const float4* __restrict__ pkall, const int* __restrict__ knn_idx,
    float* __restrict__ out) {
  __shared__ __align__(16) unsigned short hbuf[4][32][72];  // [wave][pos][ch] bf16
  __shared__ float sscore[4][32];

  const int tid = threadIdx.x;
  const int l = tid & 63;
  const int wv = tid >> 6;
  const int wid = blockIdx.x * 4 + wv;     // 0..16383
  const int pbase = wid << 5;
  const int b = pbase >> 17;
  const int n = (pbase >> 5) & (NN - 1);
  const int kk = l & 31;
  const int half = l >> 5;

  // wave-uniform query
  const float qx = p1[(b * 3 + 0) * NN + n];
  const float qy = p1[(b * 3 + 1) * NN + n];
  const float qz = p1[(b * 3 + 2) * NN + n];

  // neighbor of position kk
  const int set = kk >> 4;
  const int id = knn_idx[pbase + kk] & (NN - 1);
  const float4 rv = pkall[(size_t)(set * BB + b) * NN + id];
  const float rx = rv.x - qx, ry = rv.y - qy, rz = rv.z - qz;
  const float dist = sqrtf(fmaxf(rx * rx + ry * ry + rz * rz, 1e-12f));

  // resident W1 B-frags (8 x 16B, coalesced, L1-hot)
  const bf16x8* w1f = (const bf16x8*)(ws + OFF_W1F);
  bf16x8 w1r[8];
#pragma unroll
  for (int f = 0; f < 8; ++f) w1r[f] = w1f[f * 64 + l];

  // ---- layer 0 (fp32 VALU): this lane computes 32 of 64 channels ----
  {
    const int cb = half * 32;
    const float4* w0 = (const float4*)(ws + OFF_W0S);
    float b0v[32];
#pragma unroll
    for (int q = 0; q < 8; ++q) {
      float4 bb = ((const float4*)(ws + OFF_B0F))[half * 8 + q];
      b0v[4 * q] = bb.x; b0v[4 * q + 1] = bb.y; b0v[4 * q + 2] = bb.z; b0v[4 * q + 3] = bb.w;
    }
    unsigned pk2[16];
#pragma unroll
    for (int i = 0; i < 32; i += 2) {
      float4 wa = w0[cb + i], wb = w0[cb + i + 1];
      float ha = fmaxf(fmaf(wa.x, rx, fmaf(wa.y, ry, fmaf(wa.z, rz, fmaf(wa.w, dist, b0v[i])))), 0.f);
      float hb = fmaxf(fmaf(wb.x, rx, fmaf(wb.y, ry, fmaf(wb.z, rz, fmaf(wb.w, dist, b0v[i + 1])))), 0.f);
      pk2[i >> 1] = ((unsigned)f2bf(hb) << 16) | (unsigned)f2bf(ha);
    }
    uint4* dst = (uint4*)&hbuf[wv][kk][cb];
    dst[0] = make_uint4(pk2[0], pk2[1], pk2[2], pk2[3]);
    dst[1] = make_uint4(pk2[4], pk2[5], pk2[6], pk2[7]);
    dst[2] = make_uint4(pk2[8], pk2[9], pk2[10], pk2[11]);
    dst[3] = make_uint4(pk2[12], pk2[13], pk2[14], pk2[15]);
  }
  __syncthreads();   // fence 1: h0 writes -> A-frag reads

  // ---- layer 1: D[pos][o] = h0 . W1 (MFMA), C init = bias1[col] ----
  f32x4 c1[2][4];
  {
    float b1v[4];
#pragma unroll
    for (int nb = 0; nb < 4; ++nb) b1v[nb] = ws[OFF_B1 + nb * 16 + (l & 15)];
#pragma unroll
    for (int mb = 0; mb < 2; ++mb)
#pragma unroll
      for (int nb = 0; nb < 4; ++nb) {
        c1[mb][nb][0] = b1v[nb]; c1[mb][nb][1] = b1v[nb];
        c1[mb][nb][2] = b1v[nb]; c1[mb][nb][3] = b1v[nb];
      }
  }
  bf16x8 a1[2][2];
#pragma unroll
  for (int mb = 0; mb < 2; ++mb)
#pragma unroll
    for (int kb = 0; kb < 2; ++kb)
      a1[mb][kb] = *(const bf16x8*)&hbuf[wv][mb * 16 + (l & 15)][kb * 32 + (l >> 4) * 8];
#pragma unroll
  for (int mb = 0; mb < 2; ++mb)
#pragma unroll
    for (int nb = 0; nb < 4; ++nb)
#pragma unroll
      for (int kb = 0; kb < 2; ++kb)
        c1[mb][nb] = __builtin_amdgcn_mfma_f32_16x16x32_bf16(a1[mb][kb], w1r[kb * 4 + nb],
                                                             c1[mb][nb], 0, 0, 0);

  // epilogue: relu -> bf16 -> scatter back into hbuf (h1, same [pos][ch] layout)
#pragma unroll
  for (int mb = 0; mb < 2; ++mb)
#pragma unroll
    for (int nb = 0; nb < 4; ++nb) {
      const int ch = nb * 16 + (l & 15);
#pragma unroll
      for (int r = 0; r < 4; ++r) {
        float h = fmaxf(c1[mb][nb][r], 0.f);
        hbuf[wv][mb * 16 + (l >> 4) * 4 + r][ch] = f2bf(h);
      }
    }
  __syncthreads();   // fence 2: h1 writes -> B-frag reads

  // ---- layer 2: D2^T = W2 . h1^T, bias-as-C-init, running channel max ----
  bf16x8 b2f[2][2];
#pragma unroll
  for (int nb = 0; nb < 2; ++nb)
#pragma unroll
    for (int kb = 0; kb < 2; ++kb)
      b2f[nb][kb] = *(const bf16x8*)&hbuf[wv][nb * 16 + (l & 15)][kb * 32 + (l >> 4) * 8];

  const bf16x8* w2f = (const bf16x8*)(ws + OFF_W2F);
  f32x4 rmax[2];
  rmax[0][0] = rmax[0][1] = rmax[0][2] = rmax[0][3] = -INFINITY;
  rmax[1] = rmax[0];
#pragma unroll
  for (int mb = 0; mb < 8; ++mb) {
    bf16x8 a0 = w2f[(mb * 2 + 0) * 64 + l];
    bf16x8 a1_ = w2f[(mb * 2 + 1) * 64 + l];
    float4 bb = ((const float4*)(ws + OFF_B2))[mb * 4 + (l >> 4)];
    f32x4 cini; cini[0] = bb.x; cini[1] = bb.y; cini[2] = bb.z; cini[3] = bb.w;
#pragma unroll
    for (int nb = 0; nb < 2; ++nb) {
      f32x4 c = __builtin_amdgcn_mfma_f32_16x16x32_bf16(a0, b2f[nb][0], cini, 0, 0, 0);
      c = __builtin_amdgcn_mfma_f32_16x16x32_bf16(a1_, b2f[nb][1], c, 0, 0, 0);
#pragma unroll
      for (int r = 0; r < 4; ++r) rmax[nb][r] = fmaxf(rmax[nb][r], c[r]);
    }
  }

  // reduce rows (channels) -> score per position; relu commutes with max
#pragma unroll
  for (int nb = 0; nb < 2; ++nb) {
    float m = fmaxf(fmaxf(rmax[nb][0], rmax[nb][1]), fmaxf(rmax[nb][2], rmax[nb][3]));
    m = fmaxf(m, __shfl_xor(m, 16));
    m = fmaxf(m, __shfl_xor(m, 32));
    m = fmaxf(m, 0.f);
    if ((l >> 4) == 0) sscore[wv][nb * 16 + l] = m;
  }
  __syncthreads();   // fence 3: score writes -> score reads

  // ---- softmax over 32 kk + weighted sum of neighbor coords ----
  float sc = sscore[wv][kk];
  float gm = sc;
#pragma unroll
  for (int off = 16; off > 0; off >>= 1) gm = fmaxf(gm, __shfl_xor(gm, off));
  float e = __expf(sc - gm);
  float es = e, ex = e * rv.x, ey = e * rv.y, ez = e * rv.z;
#pragma unroll
  for (int off = 16; off > 0; off >>= 1) {
    es += __shfl_xor(es, off);
    ex += __shfl_xor(ex, off);
    ey += __shfl_xor(ey, off);
    ez += __shfl_xor(ez, off);
  }
  if (l == 0) {
    float inv = 1.f / es;
    out[(b * 3 + 0) * NN + n] = ex * inv;
    out[(b * 3 + 1) * NN + n] = ey * inv;
    out[(b * 3 + 2) * NN + n] = ez * inv;
  }
}

extern "C" void kernel_launch(void* const* d_in, const int* in_sizes, int n_in,
                              void* d_out, int out_size, void* d_ws, size_t ws_size,
                              hipStream_t stream) {
  const float* p1 = (const float*)d_in[0];
  const float* p2 = (const float*)d_in[1];
  float* ws = (float*)d_ws;
  float* out = (float*)d_out;

  prep_kernel<<<128, 256, 0, stream>>>(
      p1, p2,
      (const float*)d_in[3],  (const float*)d_in[4],  (const float*)d_in[5],
      (const float*)d_in[6],  (const float*)d_in[7],  (const float*)d_in[8],
      (const float*)d_in[9],  (const float*)d_in[10], (const float*)d_in[11],
      (const float*)d_in[12], (const float*)d_in[13], (const float*)d_in[14],
      (const float*)d_in[15], (const float*)d_in[16], (const float*)d_in[17],
      (const float*)d_in[18], (const float*)d_in[19], (const float*)d_in[20],
      ws);
  knn_kernel<<<512, 512, 0, stream>>>(p1, (const float4*)(ws + OFF_PACK),
                                      (int*)(ws + OFF_IDX));
  fusion_kernel<<<4096, 256, 0, stream>>>(p1, ws, (const float4*)(ws + OFF_PACK),
                                          (const int*)(ws + OFF_IDX), out);
}

// Round 9
// 256.165 us; speedup vs baseline: 2.5688x; 1.2301x over previous
//
#include <hip/hip_runtime.h>
#include <math.h>

#define BB 4
#define NN 4096

// workspace layout (float offsets)
#define OFF_W0S   0        // 256 fp32: w0*s0 [c][4]
#define OFF_B0F   256      // 64 fp32
#define OFF_B1    320      // 64 fp32
#define OFF_B2    384      // 128 fp32
#define OFF_W1F   512      // 4096 bf16 (2048 floats): W1 B-frags [kb*4+nb][lane][8]
#define OFF_W2F   2560     // 8192 bf16 (4096 floats): W2 A-frags [mb*2+kb][lane][8]
#define OFF_PACK  6656     // float4 refs [set][b][j] = (x,y,z,|r|^2) (131072 floats)
#define OFF_IDX   137728   // int knn idx [b][n][32] (524288 ints)

// sentinel key = key(d=+inf, idx=4095) = 0x7F800000*4096 + 4095
#define KSENT 8761733287935.0

typedef __attribute__((ext_vector_type(8))) short bf16x8;
typedef __attribute__((ext_vector_type(4))) float f32x4;

static __device__ __forceinline__ unsigned short f2bf(float f) {  // RNE
  unsigned u = __float_as_uint(f);
  unsigned r = u + 0x7FFFu + ((u >> 16) & 1u);
  return (unsigned short)(r >> 16);
}

__global__ __launch_bounds__(256) void prep_kernel(
    const float* __restrict__ p1, const float* __restrict__ p2,
    const float* __restrict__ w0, const float* __restrict__ b0, const float* __restrict__ g0,
    const float* __restrict__ be0, const float* __restrict__ m0, const float* __restrict__ v0,
    const float* __restrict__ w1, const float* __restrict__ b1, const float* __restrict__ g1,
    const float* __restrict__ be1, const float* __restrict__ m1, const float* __restrict__ v1,
    const float* __restrict__ w2, const float* __restrict__ b2, const float* __restrict__ g2,
    const float* __restrict__ be2, const float* __restrict__ m2, const float* __restrict__ v2,
    float* __restrict__ ws) {
  int gid = blockIdx.x * 256 + threadIdx.x;
  if (gid < 2 * BB * NN) {   // pack refs with |r|^2
    int set = gid >> 14;
    int rem = gid & (BB * NN - 1);
    int b = rem >> 12, j = rem & (NN - 1);
    const float* p = set ? p2 : p1;
    float x = p[(b * 3 + 0) * NN + j];
    float y = p[(b * 3 + 1) * NN + j];
    float z = p[(b * 3 + 2) * NN + j];
    ((float4*)(ws + OFF_PACK))[gid] = make_float4(x, y, z, x * x + y * y + z * z);
  }
  if (gid < 256) {                         // W0S[c][4] fp32
    int c = gid >> 2, f = gid & 3;
    float s = g0[c] / sqrtf(v0[c] + 1e-3f);
    ws[OFF_W0S + gid] = w0[c * 4 + f] * s;
  } else if (gid < 320) {                  // B0F
    int c = gid - 256;
    float s = g0[c] / sqrtf(v0[c] + 1e-3f);
    ws[OFF_B0F + c] = (b0[c] - m0[c]) * s + be0[c];
  } else if (gid < 384) {                  // B1
    int o = gid - 320;
    float s = g1[o] / sqrtf(v1[o] + 1e-3f);
    ws[OFF_B1 + o] = (b1[o] - m1[o]) * s + be1[o];
  } else if (gid < 512) {                  // B2
    int o = gid - 384;
    float s = g2[o] / sqrtf(v2[o] + 1e-3f);
    ws[OFF_B2 + o] = (b2[o] - m2[o]) * s + be2[o];
  } else if (gid < 4608) {                 // W1 B-frags bf16: B[k=c][n=o]
    int e = gid - 512;
    int f = e >> 9, rem = e & 511, l = rem >> 3, j = rem & 7;
    int nb = f & 3, kb = f >> 2;
    int o = nb * 16 + (l & 15);
    int c = kb * 32 + (l >> 4) * 8 + j;
    float s = g1[o] / sqrtf(v1[o] + 1e-3f);
    ((unsigned short*)ws)[OFF_W1F * 2 + e] = f2bf(w1[o * 64 + c] * s);
  } else if (gid < 12800) {                // W2 A-frags bf16: A[m=o][k=c]
    int e = gid - 4608;
    int f = e >> 9, rem = e & 511, l = rem >> 3, j = rem & 7;
    int mb = f >> 1, kb = f & 1;
    int o = mb * 16 + (l & 15);
    int c = kb * 32 + (l >> 4) * 8 + j;
    float s = g2[o] / sqrtf(v2[o] + 1e-3f);
    ((unsigned short*)ws)[OFF_W2F * 2 + e] = f2bf(w2[o * 64 + c] * s);
  }
}

__device__ __forceinline__ float distf(float qx, float qy, float qz, float qq,
                                       const float4& rv) {
  // pinned op order: bitwise-identical d everywhere
  float dt = fmaf(qx, rv.x, fmaf(qy, rv.y, qz * rv.z));
  return fmaxf(fmaf(-2.f, dt, qq + rv.w), 0.f);   // >=0 so d_bits is order-monotone
}

#define CE(x, y) { double lo_ = fmin(x, y); y = fmax(x, y); x = lo_; }

__device__ __forceinline__ void ins16d(double (&bd)[16], double t) {
#pragma unroll
  for (int i = 0; i < 16; ++i) { double lo = fmin(t, bd[i]); t = fmax(t, bd[i]); bd[i] = lo; }
}

// grid: 512 blocks (set|chunk|b) x 512 threads (8 ref-split waves x 64 queries).
// Fixed-cost batch selection: 8 exact f64 keys -> sort8 (Batcher 19 CE) ->
// bitonic halver vs sorted-16 (8 fmin) -> bitonic merge16 (32 CE). No
// data-dependent insert loop (kills the wave-max amplification of R8).
__global__ __launch_bounds__(512) void knn_kernel(const float* __restrict__ p1,
                                                  const float4* __restrict__ pkall,
                                                  int* __restrict__ idx_out) {
  __shared__ double skeys[512 * 17];   // 69.6 KB, pad 17 for bank spread

  const int tid = threadIdx.x;
  const int lane = tid & 63;
  const int wv = __builtin_amdgcn_readfirstlane(tid >> 6);  // split 0..7, SGPR
  const int set = blockIdx.x & 1;
  const int chunk = (blockIdx.x >> 1) & 63;
  const int b = blockIdx.x >> 7;
  const int n = (chunk << 6) | lane;

  const float qx = p1[(b * 3 + 0) * NN + n];
  const float qy = p1[(b * 3 + 1) * NN + n];
  const float qz = p1[(b * 3 + 2) * NN + n];
  const float qq = qx * qx + qy * qy + qz * qz;

  const float4* __restrict__ pk = pkall + (size_t)(set * BB + b) * NN;
  const int j0 = wv << 9;             // 512 refs per split

  double a[16];
#pragma unroll
  for (int i = 0; i < 16; ++i) a[i] = KSENT;
  float worstf = INFINITY;            // d-part of a[15]

#pragma unroll 1
  for (int jb = j0; jb < j0 + 512; jb += 8) {
    float d[8];
#pragma unroll
    for (int r = 0; r < 8; ++r) d[r] = distf(qx, qy, qz, qq, pk[jb + r]);
    // prefilter: skip network only when NO lane has a candidate (<=: equal-d,
    // lower-idx candidates must still enter)
    float m01 = fminf(d[0], d[1]), m23 = fminf(d[2], d[3]);
    float m45 = fminf(d[4], d[5]), m67 = fminf(d[6], d[7]);
    float m = fminf(fminf(m01, m23), fminf(m45, m67));
    if (m <= worstf) {
      const double jbd = (double)jb;
      double k[8];
#pragma unroll
      for (int r = 0; r < 8; ++r)
        k[r] = fma((double)__float_as_uint(d[r]), 4096.0, jbd + (double)r);
      // ---- sort8 ascending (Batcher odd-even, 19 CE) ----
      CE(k[0], k[1]); CE(k[2], k[3]); CE(k[4], k[5]); CE(k[6], k[7]);
      CE(k[0], k[2]); CE(k[1], k[3]); CE(k[4], k[6]); CE(k[5], k[7]);
      CE(k[1], k[2]); CE(k[5], k[6]);
      CE(k[0], k[4]); CE(k[1], k[5]); CE(k[2], k[6]); CE(k[3], k[7]);
      CE(k[2], k[4]); CE(k[3], k[5]);
      CE(k[1], k[2]); CE(k[3], k[4]); CE(k[5], k[6]);
      // ---- halver: keep 16 smallest of a(16)+k(8); result bitonic ----
#pragma unroll
      for (int j = 0; j < 8; ++j) a[8 + j] = fmin(a[8 + j], k[7 - j]);
      // ---- bitonic merge16 ascending (4 layers x 8 CE) ----
      CE(a[0], a[8]);  CE(a[1], a[9]);  CE(a[2], a[10]); CE(a[3], a[11]);
      CE(a[4], a[12]); CE(a[5], a[13]); CE(a[6], a[14]); CE(a[7], a[15]);
      CE(a[0], a[4]);  CE(a[1], a[5]);  CE(a[2], a[6]);  CE(a[3], a[7]);
      CE(a[8], a[12]); CE(a[9], a[13]); CE(a[10], a[14]); CE(a[11], a[15]);
      CE(a[0], a[2]);  CE(a[1], a[3]);  CE(a[4], a[6]);  CE(a[5], a[7]);
      CE(a[8], a[10]); CE(a[9], a[11]); CE(a[12], a[14]); CE(a[13], a[15]);
      CE(a[0], a[1]);  CE(a[2], a[3]);  CE(a[4], a[5]);  CE(a[6], a[7]);
      CE(a[8], a[9]);  CE(a[10], a[11]); CE(a[12], a[13]); CE(a[14], a[15]);
      worstf = __uint_as_float((unsigned)(a[15] * 0x1p-12));  // trunc -> d_bits
    }
  }

#pragma unroll
  for (int i = 0; i < 16; ++i) skeys[tid * 17 + i] = a[i];
  __syncthreads();

  // ---- merge 8 sorted lists (wave 0), write final indices ----
  if (tid < 64) {
    double md[16];
#pragma unroll
    for (int i = 0; i < 16; ++i) md[i] = skeys[tid * 17 + i];
#pragma unroll 1
    for (int s = 1; s < 8; ++s) {
      int base = ((s << 6) | tid) * 17;
#pragma unroll 1
      for (int i = 0; i < 16; ++i) {
        double t = skeys[base + i];
        if (t >= md[15]) break;   // sorted: rest can't qualify
        ins16d(md, t);
      }
    }
    const int nq = (chunk << 6) | tid;
    const int ob = (((b << 12) | nq) << 5) + (set << 4);
#pragma unroll
    for (int i = 0; i < 16; ++i) {
      unsigned db = (unsigned)(md[i] * 0x1p-12);              // d_bits
      int idx = (int)(md[i] - (double)db * 4096.0);           // exact low 12 bits
      idx_out[ob + i] = idx;
    }
  }
}

// grid: 4096 blocks x 256 (4 waves); wave = 1 query x 32 kk positions.
// Layer0 fp32 VALU -> bf16 -> LDS transpose; layers 1&2 on MFMA bf16.
__global__ __launch_bounds__(256) void fusion_kernel(
    const float* __restrict__ p1, const float* __restrict__ ws,
    const float4* __restrict__ pkall, const int* __restrict__ knn_idx,
    float* __restrict__ out) {
  __shared__ __align__(16) unsigned short hbuf[4][32][72];  // [wave][pos][ch] bf16
  __shared__ float sscore[4][32];

  const int tid = threadIdx.x;
  const int l = tid & 63;
  const int wv = tid >> 6;
  const int wid = blockIdx.x * 4 + wv;     // 0..16383
  const int pbase = wid << 5;
  const int b = pbase >> 17;
  const int n = (pbase >> 5) & (NN - 1);
  const int kk = l & 31;
  const int half = l >> 5;

  // wave-uniform query
  const float qx = p1[(b * 3 + 0) * NN + n];
  const float qy = p1[(b * 3 + 1) * NN + n];
  const float qz = p1[(b * 3 + 2) * NN + n];

  // neighbor of position kk
  const int set = kk >> 4;
  const int id = knn_idx[pbase + kk] & (NN - 1);
  const float4 rv = pkall[(size_t)(set * BB + b) * NN + id];
  const float rx = rv.x - qx, ry = rv.y - qy, rz = rv.z - qz;
  const float dist = sqrtf(fmaxf(rx * rx + ry * ry + rz * rz, 1e-12f));

  // resident W1 B-frags (8 x 16B, coalesced, L1-hot)
  const bf16x8* w1f = (const bf16x8*)(ws + OFF_W1F);
  bf16x8 w1r[8];
#pragma unroll
  for (int f = 0; f < 8; ++f) w1r[f] = w1f[f * 64 + l];

  // ---- layer 0 (fp32 VALU): this lane computes 32 of 64 channels ----
  {
    const int cb = half * 32;
    const float4* w0 = (const float4*)(ws + OFF_W0S);
    float b0v[32];
#pragma unroll
    for (int q = 0; q < 8; ++q) {
      float4 bb = ((const float4*)(ws + OFF_B0F))[half * 8 + q];
      b0v[4 * q] = bb.x; b0v[4 * q + 1] = bb.y; b0v[4 * q + 2] = bb.z; b0v[4 * q + 3] = bb.w;
    }
    unsigned pk2[16];
#pragma unroll
    for (int i = 0; i < 32; i += 2) {
      float4 wa = w0[cb + i], wb = w0[cb + i + 1];
      float ha = fmaxf(fmaf(wa.x, rx, fmaf(wa.y, ry, fmaf(wa.z, rz, fmaf(wa.w, dist, b0v[i])))), 0.f);
      float hb = fmaxf(fmaf(wb.x, rx, fmaf(wb.y, ry, fmaf(wb.z, rz, fmaf(wb.w, dist, b0v[i + 1])))), 0.f);
      pk2[i >> 1] = ((unsigned)f2bf(hb) << 16) | (unsigned)f2bf(ha);
    }
    uint4* dst = (uint4*)&hbuf[wv][kk][cb];
    dst[0] = make_uint4(pk2[0], pk2[1], pk2[2], pk2[3]);
    dst[1] = make_uint4(pk2[4], pk2[5], pk2[6], pk2[7]);
    dst[2] = make_uint4(pk2[8], pk2[9], pk2[10], pk2[11]);
    dst[3] = make_uint4(pk2[12], pk2[13], pk2[14], pk2[15]);
  }
  __syncthreads();   // fence 1: h0 writes -> A-frag reads

  // ---- layer 1: D[pos][o] = h0 . W1 (MFMA), C init = bias1[col] ----
  f32x4 c1[2][4];
  {
    float b1v[4];
#pragma unroll
    for (int nb = 0; nb < 4; ++nb) b1v[nb] = ws[OFF_B1 + nb * 16 + (l & 15)];
#pragma unroll
    for (int mb = 0; mb < 2; ++mb)
#pragma unroll
      for (int nb = 0; nb < 4; ++nb) {
        c1[mb][nb][0] = b1v[nb]; c1[mb][nb][1] = b1v[nb];
        c1[mb][nb][2] = b1v[nb]; c1[mb][nb][3] = b1v[nb];
      }
  }
  bf16x8 a1[2][2];
#pragma unroll
  for (int mb = 0; mb < 2; ++mb)
#pragma unroll
    for (int kb = 0; kb < 2; ++kb)
      a1[mb][kb] = *(const bf16x8*)&hbuf[wv][mb * 16 + (l & 15)][kb * 32 + (l >> 4) * 8];
#pragma unroll
  for (int mb = 0; mb < 2; ++mb)
#pragma unroll
    for (int nb = 0; nb < 4; ++nb)
#pragma unroll
      for (int kb = 0; kb < 2; ++kb)
        c1[mb][nb] = __builtin_amdgcn_mfma_f32_16x16x32_bf16(a1[mb][kb], w1r[kb * 4 + nb],
                                                             c1[mb][nb], 0, 0, 0);

  // epilogue: relu -> bf16 -> scatter back into hbuf (h1, same [pos][ch] layout)
#pragma unroll
  for (int mb = 0; mb < 2; ++mb)
#pragma unroll
    for (int nb = 0; nb < 4; ++nb) {
      const int ch = nb * 16 + (l & 15);
#pragma unroll
      for (int r = 0; r < 4; ++r) {
        float h = fmaxf(c1[mb][nb][r], 0.f);
        hbuf[wv][mb * 16 + (l >> 4) * 4 + r][ch] = f2bf(h);
      }
    }
  __syncthreads();   // fence 2: h1 writes -> B-frag reads

  // ---- layer 2: D2^T = W2 . h1^T, bias-as-C-init, running channel max ----
  bf16x8 b2f[2][2];
#pragma unroll
  for (int nb = 0; nb < 2; ++nb)
#pragma unroll
    for (int kb = 0; kb < 2; ++kb)
      b2f[nb][kb] = *(const bf16x8*)&hbuf[wv][nb * 16 + (l & 15)][kb * 32 + (l >> 4) * 8];

  const bf16x8* w2f = (const bf16x8*)(ws + OFF_W2F);
  f32x4 rmax[2];
  rmax[0][0] = rmax[0][1] = rmax[0][2] = rmax[0][3] = -INFINITY;
  rmax[1] = rmax[0];
#pragma unroll
  for (int mb = 0; mb < 8; ++mb) {
    bf16x8 a0 = w2f[(mb * 2 + 0) * 64 + l];
    bf16x8 a1_ = w2f[(mb * 2 + 1) * 64 + l];
    float4 bb = ((const float4*)(ws + OFF_B2))[mb * 4 + (l >> 4)];
    f32x4 cini; cini[0] = bb.x; cini[1] = bb.y; cini[2] = bb.z; cini[3] = bb.w;
#pragma unroll
    for (int nb = 0; nb < 2; ++nb) {
      f32x4 c = __builtin_amdgcn_mfma_f32_16x16x32_bf16(a0, b2f[nb][0], cini, 0, 0, 0);
      c = __builtin_amdgcn_mfma_f32_16x16x32_bf16(a1_, b2f[nb][1], c, 0, 0, 0);
#pragma unroll
      for (int r = 0; r < 4; ++r) rmax[nb][r] = fmaxf(rmax[nb][r], c[r]);
    }
  }

  // reduce rows (channels) -> score per position; relu commutes with max
#pragma unroll
  for (int nb = 0; nb < 2; ++nb) {
    float m = fmaxf(fmaxf(rmax[nb][0], rmax[nb][1]), fmaxf(rmax[nb][2], rmax[nb][3]));
    m = fmaxf(m, __shfl_xor(m, 16));
    m = fmaxf(m, __shfl_xor(m, 32));
    m = fmaxf(m, 0.f);
    if ((l >> 4) == 0) sscore[wv][nb * 16 + l] = m;
  }
  __syncthreads();   // fence 3: score writes -> score reads

  // ---- softmax over 32 kk + weighted sum of neighbor coords ----
  float sc = sscore[wv][kk];
  float gm = sc;
#pragma unroll
  for (int off = 16; off > 0; off >>= 1) gm = fmaxf(gm, __shfl_xor(gm, off));
  float e = __expf(sc - gm);
  float es = e, ex = e * rv.x, ey = e * rv.y, ez = e * rv.z;
#pragma unroll
  for (int off = 16; off > 0; off >>= 1) {
    es += __shfl_xor(es, off);
    ex += __shfl_xor(ex, off);
    ey += __shfl_xor(ey, off);
    ez += __shfl_xor(ez, off);
  }
  if (l == 0) {
    float inv = 1.f / es;
    out[(b * 3 + 0) * NN + n] = ex * inv;
    out[(b * 3 + 1) * NN + n] = ey * inv;
    out[(b * 3 + 2) * NN + n] = ez * inv;
  }
}

extern "C" void kernel_launch(void* const* d_in, const int* in_sizes, int n_in,
                              void* d_out, int out_size, void* d_ws, size_t ws_size,
                              hipStream_t stream) {
  const float* p1 = (const float*)d_in[0];
  const float* p2 = (const float*)d_in[1];
  float* ws = (float*)d_ws;
  float* out = (float*)d_out;

  prep_kernel<<<128, 256, 0, stream>>>(
      p1, p2,
      (const float*)d_in[3],  (const float*)d_in[4],  (const float*)d_in[5],
      (const float*)d_in[6],  (const float*)d_in[7],  (const float*)d_in[8],
      (const float*)d_in[9],  (const float*)d_in[10], (const float*)d_in[11],
      (const float*)d_in[12], (const float*)d_in[13], (const float*)d_in[14],
      (const float*)d_in[15], (const float*)d_in[16], (const float*)d_in[17],
      (const float*)d_in[18], (const float*)d_in[19], (const float*)d_in[20],
      ws);
  knn_kernel<<<512, 512, 0, stream>>>(p1, (const float4*)(ws + OFF_PACK),
                                      (int*)(ws + OFF_IDX));
  fusion_kernel<<<4096, 256, 0, stream>>>(p1, ws, (const float4*)(ws + OFF_PACK),
                                          (const int*)(ws + OFF_IDX), out);
}